// Round 1
// 540.152 us; speedup vs baseline: 1.0151x; 1.0151x over previous
//
#include <hip/hip_runtime.h>
#include <stdint.h>

#define Bn 16
#define C 64
#define H 256
#define W 256
#define HW (H * W)          // 65536
#define NHW (Bn * HW)       // 1048576
#define PPT 4               // pixels per thread (horizontal, along w)

typedef float f32x4 __attribute__((ext_vector_type(4)));

// ---------------------------------------------------------------------------
// Kernel 1: weight prep. One wave per output channel o.
// wbits[o*9+tap] bit c = (w[o][c][tap] > 0); scale[o] = mean|w| over 576.
// edgeL[o]/edgeR[o] = 2 * sum popc over the left/right column taps — used to
// correct the unmasked popcount sum at image column borders.
// ---------------------------------------------------------------------------
__global__ void prep_weights(const float* __restrict__ w,
                             uint64_t* __restrict__ wbits,
                             float* __restrict__ scale,
                             int* __restrict__ edgeL,
                             int* __restrict__ edgeR) {
    int o = blockIdx.x;     // 64 blocks
    int c = threadIdx.x;    // 64 threads = 1 wave
    const float* wp = w + ((size_t)o * C + c) * 9;
    float asum = 0.f;
    uint64_t m[9];
#pragma unroll
    for (int tap = 0; tap < 9; ++tap) {
        float v = wp[tap];
        asum += fabsf(v);
        m[tap] = __ballot(v > 0.f);   // uniform across the wave
    }
    if (c == 0) {
#pragma unroll
        for (int tap = 0; tap < 9; ++tap) wbits[o * 9 + tap] = m[tap];
        edgeL[o] = 2 * (int)(__popcll(m[0]) + __popcll(m[3]) + __popcll(m[6]));
        edgeR[o] = 2 * (int)(__popcll(m[2]) + __popcll(m[5]) + __popcll(m[8]));
    }
#pragma unroll
    for (int off = 32; off > 0; off >>= 1)
        asum += __shfl_down(asum, off);
    if (c == 0) scale[o] = asum * (1.f / 576.f);
}

// ---------------------------------------------------------------------------
// Kernel 2: pack z = sign(x + bias). 4 pixels/thread, float4 loads (16B/lane).
// ---------------------------------------------------------------------------
__global__ __launch_bounds__(256) void pack_z(const float* __restrict__ x,
                                              const float* __restrict__ bias,
                                              uint64_t* __restrict__ zbits) {
    int t = blockIdx.x * 256 + threadIdx.x;   // NHW/PPT threads total
    int p0 = t * PPT;
    int n = p0 >> 16;                         // / HW
    int hw = p0 & (HW - 1);
    const float* xp = x + (size_t)n * C * HW + hw;
    uint64_t b0 = 0, b1 = 0, b2 = 0, b3 = 0;
#pragma unroll 8
    for (int c = 0; c < C; ++c) {
        f32x4 v = *reinterpret_cast<const f32x4*>(xp + (size_t)c * HW);
        float bc = bias[c];                   // uniform -> scalar load
        b0 |= (uint64_t)(v.x + bc > 0.f) << c;
        b1 |= (uint64_t)(v.y + bc > 0.f) << c;
        b2 |= (uint64_t)(v.z + bc > 0.f) << c;
        b3 |= (uint64_t)(v.w + bc > 0.f) << c;
    }
    ulonglong2* zp = reinterpret_cast<ulonglong2*>(zbits + p0);
    zp[0] = make_ulonglong2(b0, b1);
    zp[1] = make_ulonglong2(b2, b3);
}

// ---------------------------------------------------------------------------
// Kernel 3: binary conv + RPReLU + residual. Thread = 4 horizontal pixels,
// all 64 output channels. Weights read from LDS once per o, reused 4x.
// Interior rows: unmasked popcounts (invalid z-words are 0), with a tiny
// exec-masked edge correction on lanes w0==0 / w0==252.
// ---------------------------------------------------------------------------
__global__ __launch_bounds__(256) void bconv(const uint64_t* __restrict__ zbits,
                                             const uint64_t* __restrict__ wbits,
                                             const float* __restrict__ scale,
                                             const int* __restrict__ edgeL,
                                             const int* __restrict__ edgeR,
                                             const float* __restrict__ x,
                                             const float* __restrict__ pb0,
                                             const float* __restrict__ aw,
                                             const float* __restrict__ pb1,
                                             float* __restrict__ out) {
    __shared__ uint64_t swb[576];
    __shared__ float sscale[C], spb0[C], sa[C], spb1[C];
    __shared__ int sEL[C], sER[C];
    int t = threadIdx.x;
    if (t < C) {
        sscale[t] = scale[t];
        spb0[t]   = pb0[t];
        sa[t]     = aw[t];
        spb1[t]   = pb1[t];
        sEL[t]    = edgeL[t];
        sER[t]    = edgeR[t];
    }
    for (int i = t; i < 576; i += 256) swb[i] = wbits[i];
    __syncthreads();

    int p0 = (blockIdx.x * 256 + t) * PPT;
    int n  = p0 >> 16;
    int hw = p0 & (HW - 1);
    int h  = hw >> 8;           // W = 256
    int w0 = hw & (W - 1);      // multiple of 4

    // 3 rows x 6 columns of z-words cover taps for 4 consecutive pixels.
    const uint64_t* zr = zbits + (size_t)n * HW;
    uint64_t zb[3][6];
#pragma unroll
    for (int i = 0; i < 3; ++i) {
        int hh = h - 1 + i;
        bool rv = (unsigned)hh < (unsigned)H;
#pragma unroll
        for (int j = 0; j < 6; ++j) {
            int cc = w0 - 1 + j;
            bool cv = (unsigned)cc < (unsigned)W;
            zb[i][j] = (rv && cv) ? zr[hh * W + cc] : 0ull;
        }
    }

    const float* xid = x + (size_t)n * C * HW + hw;
    float* op = out + (size_t)n * C * HW + hw;

    bool leftE  = (w0 == 0);
    bool rightE = (w0 == W - PPT);

    if (h >= 1 && h <= H - 2) {
        // -------- fast path: all rows valid (254/256 of waves) --------
#pragma unroll 2
        for (int o = 0; o < C; ++o) {
            const uint64_t* wp = &swb[o * 9];
            int s0 = 0, s1 = 0, s2 = 0, s3 = 0;
#pragma unroll
            for (int i = 0; i < 3; ++i)
#pragma unroll
                for (int jj = 0; jj < 3; ++jj) {
                    uint64_t wt = wp[i * 3 + jj];
                    s0 += (int)__popcll(wt ^ zb[i][jj]);
                    s1 += (int)__popcll(wt ^ zb[i][jj + 1]);
                    s2 += (int)__popcll(wt ^ zb[i][jj + 2]);
                    s3 += (int)__popcll(wt ^ zb[i][jj + 3]);
                }
            int d0 = 576 - 2 * s0, d1 = 576 - 2 * s1;
            int d2 = 576 - 2 * s2, d3 = 576 - 2 * s3;
            // column-border correction: nv=6 taps -> base 384, add back the
            // weight-popcounts the unmasked sum wrongly included.
            if (leftE)  d0 += sEL[o] - 192;
            if (rightE) d3 += sER[o] - 192;

            float sc = sscale[o], bb0 = spb0[o], af = sa[o], bb1 = spb1[o];
            f32x4 idv = *reinterpret_cast<const f32x4*>(xid + (size_t)o * HW);
            f32x4 r;
            float y;
            y = sc * (float)d0 + bb0; y = y > 0.f ? y : af * y; r.x = y + bb1 + idv.x;
            y = sc * (float)d1 + bb0; y = y > 0.f ? y : af * y; r.y = y + bb1 + idv.y;
            y = sc * (float)d2 + bb0; y = y > 0.f ? y : af * y; r.z = y + bb1 + idv.z;
            y = sc * (float)d3 + bb0; y = y > 0.f ? y : af * y; r.w = y + bb1 + idv.w;
            __builtin_nontemporal_store(r, reinterpret_cast<f32x4*>(op + (size_t)o * HW));
        }
    } else {
        // -------- slow path: h==0 or h==255 (2/256 of waves), fully masked --
        int vrow[3], vcol[6];
#pragma unroll
        for (int i = 0; i < 3; ++i)
            vrow[i] = ((unsigned)(h - 1 + i) < (unsigned)H) ? -1 : 0;
#pragma unroll
        for (int j = 0; j < 6; ++j)
            vcol[j] = ((unsigned)(w0 - 1 + j) < (unsigned)W) ? -1 : 0;
        int nv[4];
#pragma unroll
        for (int q = 0; q < 4; ++q) {
            int nr = (vrow[0] & 1) + (vrow[1] & 1) + (vrow[2] & 1);
            int nc = (vcol[q] & 1) + (vcol[q + 1] & 1) + (vcol[q + 2] & 1);
            nv[q] = nr * nc;
        }
#pragma unroll 2
        for (int o = 0; o < C; ++o) {
            const uint64_t* wp = &swb[o * 9];
            int s[4] = {0, 0, 0, 0};
#pragma unroll
            for (int i = 0; i < 3; ++i)
#pragma unroll
                for (int jj = 0; jj < 3; ++jj) {
                    uint64_t wt = wp[i * 3 + jj];
#pragma unroll
                    for (int q = 0; q < 4; ++q)
                        s[q] += (vrow[i] & vcol[q + jj]) &
                                (int)__popcll(wt ^ zb[i][q + jj]);
                }
            float sc = sscale[o], bb0 = spb0[o], af = sa[o], bb1 = spb1[o];
            f32x4 idv = *reinterpret_cast<const f32x4*>(xid + (size_t)o * HW);
            f32x4 r;
            float y;
            y = sc * (float)(64 * nv[0] - 2 * s[0]) + bb0; y = y > 0.f ? y : af * y; r.x = y + bb1 + idv.x;
            y = sc * (float)(64 * nv[1] - 2 * s[1]) + bb0; y = y > 0.f ? y : af * y; r.y = y + bb1 + idv.y;
            y = sc * (float)(64 * nv[2] - 2 * s[2]) + bb0; y = y > 0.f ? y : af * y; r.z = y + bb1 + idv.z;
            y = sc * (float)(64 * nv[3] - 2 * s[3]) + bb0; y = y > 0.f ? y : af * y; r.w = y + bb1 + idv.w;
            __builtin_nontemporal_store(r, reinterpret_cast<f32x4*>(op + (size_t)o * HW));
        }
    }
}

// ---------------------------------------------------------------------------
extern "C" void kernel_launch(void* const* d_in, const int* in_sizes, int n_in,
                              void* d_out, int out_size, void* d_ws, size_t ws_size,
                              hipStream_t stream) {
    const float* x           = (const float*)d_in[0];
    const float* move0_bias  = (const float*)d_in[1];
    const float* conv_weight = (const float*)d_in[2];
    const float* prelu_w     = (const float*)d_in[3];
    const float* pr_bias0    = (const float*)d_in[4];
    const float* pr_bias1    = (const float*)d_in[5];
    float* out = (float*)d_out;

    uint8_t* ws = (uint8_t*)d_ws;
    uint64_t* zbits = (uint64_t*)ws;                                   // 8 MB
    uint64_t* wbits = (uint64_t*)(ws + (size_t)NHW * 8);               // 4608 B
    float* scale    = (float*)(ws + (size_t)NHW * 8 + 576 * 8);        // 256 B
    int* edgeL      = (int*)(ws + (size_t)NHW * 8 + 576 * 8 + 256);    // 256 B
    int* edgeR      = (int*)(ws + (size_t)NHW * 8 + 576 * 8 + 512);    // 256 B

    prep_weights<<<64, 64, 0, stream>>>(conv_weight, wbits, scale, edgeL, edgeR);
    pack_z<<<NHW / PPT / 256, 256, 0, stream>>>(x, move0_bias, zbits);
    bconv<<<NHW / PPT / 256, 256, 0, stream>>>(zbits, wbits, scale, edgeL, edgeR,
                                               x, pr_bias0, prelu_w, pr_bias1, out);
}